// Round 4
// baseline (793.217 us; speedup 1.0000x reference)
//
#include <hip/hip_runtime.h>
#include <hip/hip_cooperative_groups.h>

namespace cg = cooperative_groups;

#define B_ 16
#define T_ 4096
#define D_ 768
#define NBOX 1024
#define MAXBB 128

typedef unsigned short u16;
typedef short bf16x8 __attribute__((ext_vector_type(8)));
typedef float f32x4 __attribute__((ext_vector_type(4)));

// round-to-nearest-even fp32 -> bf16 split: f ~= hi + lo (both bf16)
__device__ __forceinline__ void split_bf(float f, u16& h, u16& l) {
    unsigned u = __builtin_bit_cast(unsigned, f);
    unsigned r = u + 0x7fffu + ((u >> 16) & 1u);
    u16 hb = (u16)(r >> 16);
    float hf = __builtin_bit_cast(float, (unsigned)hb << 16);
    float lf = f - hf;
    unsigned ul = __builtin_bit_cast(unsigned, lf);
    unsigned rl = ul + 0x7fffu + ((ul >> 16) & 1u);
    h = hb; l = (u16)(rl >> 16);
}

struct Pr {
    const float* inputs; const int* bboxes; const float* features;
    const float *t1w, *t1b, *t2w, *t2b, *d1w, *d1b, *d2w, *d2b;
    const float *m1w, *m1b, *m2w, *m2b, *pw, *pb;
    float *vis, *att, *retx;
    float* wsf;
};

// ---- u16-region offsets (units of u16) ----
enum : size_t {
    W6   = 589824,                       // 768*768
    U_T1H = 0,            U_T1L = U_T1H + W6,
    U_T2H = U_T1L + W6,   U_T2L = U_T2H + W6,
    U_D1H = U_T2L + W6,   U_D1L = U_D1H + W6,
    U_D2H = U_D1L + W6,   U_D2L = U_D2H + W6,
    U_M1H = U_D2L + W6,   U_M1L = U_M1H + 196608,
    U_M2H = U_M1L + 196608, U_M2L = U_M2H + W6,
    U_PWH = U_M2L + W6,   U_PWL = U_PWH + 1179648,
    U_FEH = U_PWL + 1179648, U_FEL = U_FEH + 262144,
    U_F1H = U_FEL + 262144,  U_F1L = U_F1H + 786432,
    U_FMH = U_F1L + 786432,  U_FML = U_FMH + 786432,
    U_XPH = U_FML + 786432,  U_XPL = U_XPH + 12288,
    U_XCH = U_XPL + 12288,   U_XCL = U_XCH + 24576,
    U_XTH = U_XCL + 24576,   U_XTL = U_XTH + 12288
};
// ---- fp32-region offsets (units of float) ----
enum : size_t {
    F_PART = 0,
    F_P0   = 786432,                 // 2 slabs of 1024*768
    F_PS   = F_P0 + 2 * 786432,      // 16*1536
    F_CNT  = F_PS + 24576,           // 32 ints (pad to 64 floats)
    F_U16  = F_CNT + 64
};

// ======== 64x64 MFMA wave tile, 3-term in-register, optional gathered A =====
template<int GATHER>
__device__ __forceinline__ void big_wave(const u16* Ah, const u16* Al, int KcA, int akc0,
                                         const u16* Wh, const u16* Wl, int KcW, int wkc0,
                                         int nst, int mt0, int nt0, int lane,
                                         const int* bboxes, float* Pz) {
    f32x4 acc[16];
    #pragma unroll
    for (int i = 0; i < 16; ++i) acc[i] = (f32x4){0.f, 0.f, 0.f, 0.f};
    int img[4];
    if (GATHER) {
        #pragma unroll
        for (int i = 0; i < 4; ++i) img[i] = bboxes[((mt0 + i) * 16 + (lane & 15)) * 5];
    }
    #pragma unroll
    for (int term = 0; term < 3; ++term) {
        const u16* A = (term == 2) ? Al : Ah;
        const u16* W = (term == 1) ? Wl : Wh;
        const u16* Ap[4]; const u16* Wp[4];
        #pragma unroll
        for (int i = 0; i < 4; ++i) {
            if (GATHER) Ap[i] = A + ((size_t)(akc0 + (lane >> 4)) * 16 + img[i]) * 8;
            else        Ap[i] = A + ((size_t)(mt0 + i) * KcA + akc0) * 128 + lane * 8;
            Wp[i] = W + ((size_t)(nt0 + i) * KcW + wkc0) * 128 + lane * 8;
        }
        bf16x8 a[4], b[4];
        #pragma unroll
        for (int i = 0; i < 4; ++i) { a[i] = *(const bf16x8*)Ap[i]; b[i] = *(const bf16x8*)Wp[i]; }
        for (int k = 0; k < nst; ++k) {
            bf16x8 an[4], bn[4];
            if (k + 1 < nst) {
                #pragma unroll
                for (int i = 0; i < 4; ++i) {
                    an[i] = *(const bf16x8*)(Ap[i] + (size_t)(k + 1) * 512);
                    bn[i] = *(const bf16x8*)(Wp[i] + (size_t)(k + 1) * 512);
                }
            }
            #pragma unroll
            for (int i = 0; i < 4; ++i)
                #pragma unroll
                for (int j = 0; j < 4; ++j)
                    acc[i * 4 + j] = __builtin_amdgcn_mfma_f32_16x16x32_bf16(a[i], b[j], acc[i * 4 + j], 0, 0, 0);
            #pragma unroll
            for (int i = 0; i < 4; ++i) { a[i] = an[i]; b[i] = bn[i]; }
        }
    }
    int rb = (lane >> 4) * 4, cb = lane & 15;
    #pragma unroll
    for (int i = 0; i < 4; ++i)
        #pragma unroll
        for (int j = 0; j < 4; ++j) {
            float* pp = Pz + (size_t)((mt0 + i) * 16 + rb) * 768 + (nt0 + j) * 16 + cb;
            f32x4 v = acc[i * 4 + j];
            #pragma unroll
            for (int r = 0; r < 4; ++r) pp[(size_t)r * 768] = v[r];
        }
}

// ======== 16x64 MFMA wave tile (small-M chain), 3-term in-register ==========
__device__ __forceinline__ void small_wave(const u16* Ah, const u16* Al,
                                           const u16* Wh, const u16* Wl,
                                           int KcW, int nst, int ntloc, int nt0g,
                                           int lane, float* Ps) {
    f32x4 acc[4];
    #pragma unroll
    for (int j = 0; j < 4; ++j) acc[j] = (f32x4){0.f, 0.f, 0.f, 0.f};
    #pragma unroll
    for (int term = 0; term < 3; ++term) {
        const u16* A = (term == 2) ? Al : Ah;
        const u16* W = (term == 1) ? Wl : Wh;
        const u16* Ap = A + lane * 8;
        const u16* Wp = W + (size_t)ntloc * KcW * 128 + lane * 8;
        for (int k = 0; k < nst; ++k) {
            bf16x8 a = *(const bf16x8*)(Ap + (size_t)k * 512);
            #pragma unroll
            for (int j = 0; j < 4; ++j) {
                bf16x8 b = *(const bf16x8*)(Wp + (size_t)j * KcW * 128 + (size_t)k * 512);
                acc[j] = __builtin_amdgcn_mfma_f32_16x16x32_bf16(a, b, acc[j], 0, 0, 0);
            }
        }
    }
    int rb = (lane >> 4) * 4, cb = lane & 15;
    #pragma unroll
    for (int j = 0; j < 4; ++j) {
        int col = (nt0g + j) * 16 + cb;
        #pragma unroll
        for (int r = 0; r < 4; ++r) Ps[(size_t)(rb + r) * 1536 + col] = acc[j][r];
    }
}

// ======== pack fp32 GEMM out (1024x768, NS slabs) -> tiled bf16 hi/lo =======
__device__ __forceinline__ void packP(const float* P0, int NS, const float* bias, int relu,
                                      u16* dh, u16* dl, int KcDst, int kcOff, int it) {
    int m = it / 96, kc = it - m * 96;
    const float* s = P0 + (size_t)m * 768 + kc * 8;
    f32x4 v0 = *(const f32x4*)s, v1 = *(const f32x4*)(s + 4);
    if (NS == 2) {
        const float* s2 = s + 786432;
        v0 += *(const f32x4*)s2; v1 += *(const f32x4*)(s2 + 4);
    }
    v0 += *(const f32x4*)(bias + kc * 8);
    v1 += *(const f32x4*)(bias + kc * 8 + 4);
    bf16x8 hv, lv;
    #pragma unroll
    for (int j = 0; j < 4; ++j) {
        float a = relu ? fmaxf(v0[j], 0.f) : v0[j];
        float b = relu ? fmaxf(v1[j], 0.f) : v1[j];
        u16 h, l;
        split_bf(a, h, l); hv[j] = (short)h; lv[j] = (short)l;
        split_bf(b, h, l); hv[4 + j] = (short)h; lv[4 + j] = (short)l;
    }
    size_t off = ((size_t)(m >> 4) * KcDst + kcOff + kc) * 128 + (m & 15) * 8;
    *(bf16x8*)(dh + off) = hv;
    *(bf16x8*)(dl + off) = lv;
}

__global__ __launch_bounds__(256, 2) void k_fused(Pr p) {
    cg::grid_group grid = cg::this_grid();
    const int NB = gridDim.x;
    const int TOT = NB * 256;
    const int tg = blockIdx.x * 256 + threadIdx.x;
    const int lane = threadIdx.x & 63;
    const int wvl = threadIdx.x >> 6;
    const int wv = wvl * NB + blockIdx.x;   // spread wave-item id

    float* part = p.wsf + F_PART;
    float* P0   = p.wsf + F_P0;
    float* Ps   = p.wsf + F_PS;
    int*   cntg = (int*)(p.wsf + F_CNT);
    int*   offg = cntg + 16;
    u16*   U    = (u16*)(p.wsf + F_U16);

    __shared__ int scnt[B_];
    __shared__ int soff[B_];

    // =========== Ph0: mean-partials + all packs + meta (independent) =========
    {   // mean partial: 16*64 chunks x 192 f4-cols
        const float4* in4 = (const float4*)p.inputs;
        for (int it = tg; it < 196608; it += TOT) {
            int chunk = it / 192, t = it - chunk * 192;
            int b = chunk >> 6, cs = chunk & 63;
            const float4* base = in4 + (size_t)b * (T_ * D_ / 4) + (size_t)cs * 12288 + t;
            float4 s = {0.f, 0.f, 0.f, 0.f};
            #pragma unroll 4
            for (int r = 0; r < 64; ++r) {
                float4 v = base[(size_t)r * 192];
                s.x += v.x; s.y += v.y; s.z += v.z; s.w += v.w;
            }
            ((float4*)part)[it] = s;
        }
    }
    {   // weight packs: 7 matrices
        const float* srcs[7] = {p.t1w, p.t2w, p.d1w, p.d2w, p.m1w, p.m2w, p.pw};
        u16* his[7] = {U + U_T1H, U + U_T2H, U + U_D1H, U + U_D2H, U + U_M1H, U + U_M2H, U + U_PWH};
        u16* los[7] = {U + U_T1L, U + U_T2L, U + U_D1L, U + U_D2L, U + U_M1L, U + U_M2L, U + U_PWL};
        const int Kcs[7] = {96, 96, 96, 96, 32, 96, 192};
        #pragma unroll 1
        for (int mi = 0; mi < 7; ++mi) {
            int Kc = Kcs[mi];
            int cnt = 768 * Kc;
            const float* src = srcs[mi];
            u16 *dh = his[mi], *dl = los[mi];
            for (int it = tg; it < cnt; it += TOT) {
                int n = it / Kc, kc = it - n * Kc;
                const float* s = src + (size_t)n * (Kc * 8) + kc * 8;
                f32x4 v0 = *(const f32x4*)s, v1 = *(const f32x4*)(s + 4);
                bf16x8 hv, lv;
                #pragma unroll
                for (int j = 0; j < 4; ++j) {
                    u16 h, l;
                    split_bf(v0[j], h, l); hv[j] = (short)h; lv[j] = (short)l;
                    split_bf(v1[j], h, l); hv[4 + j] = (short)h; lv[4 + j] = (short)l;
                }
                size_t off = ((size_t)(n >> 4) * Kc + kc) * 128 + (n & 15) * 8;
                *(bf16x8*)(dh + off) = hv;
                *(bf16x8*)(dl + off) = lv;
            }
        }
    }
    {   // feat pack (misaligned stride-257 source)
        for (int it = tg; it < NBOX * 32; it += TOT) {
            int i = it >> 5, kc = it & 31;
            const float* s = p.features + (size_t)i * 257 + 1 + kc * 8;
            bf16x8 hv, lv;
            #pragma unroll
            for (int j = 0; j < 8; ++j) {
                u16 h, l;
                split_bf(s[j], h, l); hv[j] = (short)h; lv[j] = (short)l;
            }
            size_t off = ((size_t)(i >> 4) * 32 + kc) * 128 + (i & 15) * 8;
            *(bf16x8*)(U + U_FEH + off) = hv;
            *(bf16x8*)(U + U_FEL + off) = lv;
        }
    }
    if (blockIdx.x == 0) {   // meta: counts / offsets / att_mask
        int tid = threadIdx.x;
        if (tid < B_) scnt[tid] = 0;
        __syncthreads();
        for (int i = tid; i < NBOX; i += 256) atomicAdd(&scnt[p.bboxes[i * 5]], 1);
        __syncthreads();
        if (tid == 0) {
            int acc = 0;
            for (int b = 0; b < B_; ++b) { soff[b] = acc; acc += scnt[b]; }
        }
        __syncthreads();
        if (tid < B_) { cntg[tid] = scnt[tid]; offg[tid] = soff[tid]; }
        for (int j = tid; j < B_ * MAXBB; j += 256) {
            int b = j >> 7, q = j & 127;
            p.att[j] = (q < scnt[b]) ? 1.0f : 0.0f;
        }
    }
    grid.sync();

    // =========== Ph1: mean final + pack x ====================================
    for (int it = tg; it < 1536; it += TOT) {
        int b = it / 96, kc = it - b * 96;
        f32x4 s0 = {0,0,0,0}, s1 = {0,0,0,0};
        for (int c = 0; c < 64; ++c) {
            const float* q = part + (size_t)(b * 64 + c) * 768 + kc * 8;
            s0 += *(const f32x4*)q; s1 += *(const f32x4*)(q + 4);
        }
        const float inv = 1.0f / T_;
        bf16x8 hv, lv;
        #pragma unroll
        for (int j = 0; j < 4; ++j) {
            u16 h, l;
            split_bf(s0[j] * inv, h, l); hv[j] = (short)h; lv[j] = (short)l;
            split_bf(s1[j] * inv, h, l); hv[4 + j] = (short)h; lv[4 + j] = (short)l;
        }
        size_t off = ((size_t)kc * 16 + b) * 8;
        *(bf16x8*)(U + U_XPH + off) = hv;
        *(bf16x8*)(U + U_XPL + off) = lv;
    }
    grid.sync();

    // =========== Ph2: small layer1 + fm1 GEMM ================================
    if (wv < 24) {
        int nt0g = wv * 4;
        int path = nt0g >= 48;
        int ntloc = nt0g - 48 * path;
        small_wave(U + U_XPH, U + U_XPL,
                   U + (path ? U_T1H : U_D1H), U + (path ? U_T1L : U_D1L),
                   96, 24, ntloc, nt0g, lane, Ps);
    } else if (wv < 216) {
        int t = wv - 24;
        big_wave<0>(U + U_FEH, U + U_FEL, 32, 0,
                    U + U_M1H, U + U_M1L, 32, 0,
                    8, (t / 12) * 4, (t % 12) * 4, lane, nullptr, P0);
    }
    grid.sync();

    // =========== Ph3: sepi1 (xc pack) + fm1 pack =============================
    for (int it = tg; it < 3072 + 98304; it += TOT) {
        if (it < 3072) {
            int r = it / 192, cc = it - r * 192;
            const float* q = Ps + (size_t)r * 1536 + cc * 8;
            f32x4 s0 = *(const f32x4*)q, s1 = *(const f32x4*)(q + 4);
            int path = cc >= 96;
            int ccp = cc - path * 96;
            const float* bias = (path ? p.t1b : p.d1b) + ccp * 8;
            s0 += *(const f32x4*)bias; s1 += *(const f32x4*)(bias + 4);
            bf16x8 hv, lv;
            #pragma unroll
            for (int j = 0; j < 4; ++j) {
                u16 h, l;
                split_bf(fmaxf(s0[j], 0.f), h, l); hv[j] = (short)h; lv[j] = (short)l;
                split_bf(fmaxf(s1[j], 0.f), h, l); hv[4 + j] = (short)h; lv[4 + j] = (short)l;
            }
            size_t off = (size_t)path * 12288 + ((size_t)ccp * 16 + r) * 8;
            *(bf16x8*)(U + U_XCH + off) = hv;
            *(bf16x8*)(U + U_XCL + off) = lv;
        } else {
            packP(P0, 1, p.m1b, 1, U + U_F1H, U + U_F1L, 96, 0, it - 3072);
        }
    }
    grid.sync();

    // =========== Ph4: small layer2 + fm GEMM (KS=2) ==========================
    if (wv < 24) {
        int nt0g = wv * 4;
        int path = nt0g >= 48;
        int ntloc = nt0g - 48 * path;
        small_wave(U + U_XCH + path * 12288, U + U_XCL + path * 12288,
                   U + (path ? U_T2H : U_D2H), U + (path ? U_T2L : U_D2L),
                   96, 24, ntloc, nt0g, lane, Ps);
    } else if (wv < 408) {
        int u = wv - 24;
        int z = u / 192, tt = u - z * 192;
        big_wave<0>(U + U_F1H, U + U_F1L, 96, z * 48,
                    U + U_M2H, U + U_M2L, 96, z * 48,
                    12, (tt / 12) * 4, (tt % 12) * 4, lane, nullptr, P0 + (size_t)z * 786432);
    }
    grid.sync();

    // =========== Ph5: sepi2 (retx + xt pack) + fm pack (NS=2) ================
    for (int it = tg; it < 3072 + 98304; it += TOT) {
        if (it < 3072) {
            int r = it / 192, cc = it - r * 192;
            const float* q = Ps + (size_t)r * 1536 + cc * 8;
            f32x4 s0 = *(const f32x4*)q, s1 = *(const f32x4*)(q + 4);
            int path = cc >= 96;
            int ccp = cc - path * 96;
            const float* bias = (path ? p.t2b : p.d2b) + ccp * 8;
            s0 += *(const f32x4*)bias; s1 += *(const f32x4*)(bias + 4);
            if (!path) {
                float* o = p.retx + (size_t)r * 768 + ccp * 8;
                *(f32x4*)o = s0; *(f32x4*)(o + 4) = s1;
            } else {
                bf16x8 hv, lv;
                #pragma unroll
                for (int j = 0; j < 4; ++j) {
                    u16 h, l;
                    split_bf(s0[j], h, l); hv[j] = (short)h; lv[j] = (short)l;
                    split_bf(s1[j], h, l); hv[4 + j] = (short)h; lv[4 + j] = (short)l;
                }
                size_t off = ((size_t)ccp * 16 + r) * 8;
                *(bf16x8*)(U + U_XTH + off) = hv;
                *(bf16x8*)(U + U_XTL + off) = lv;
            }
        } else {
            packP(P0, 2, p.m2b, 0, U + U_FMH, U + U_FML, 96, 0, it - 3072);
        }
    }
    grid.sync();

    // =========== Ph6: h GEMM (KS=2: z0 = gathered xt half, z1 = fm half) =====
    if (wv < 384) {
        int z = wv / 192, tt = wv - z * 192;
        int mt0 = (tt / 12) * 4, nt0 = (tt % 12) * 4;
        if (z == 0)
            big_wave<1>(U + U_XTH, U + U_XTL, 96, 0,
                        U + U_PWH, U + U_PWL, 192, 0,
                        24, mt0, nt0, lane, p.bboxes, P0);
        else
            big_wave<0>(U + U_FMH, U + U_FML, 96, 0,
                        U + U_PWH, U + U_PWL, 192, 96,
                        24, mt0, nt0, lane, nullptr, P0 + 786432);
    }
    grid.sync();

    // =========== Ph7: vis epilogue (sum 2 slabs + pb, scatter-by-slot) =======
    for (int it = tg; it < B_ * MAXBB * 192; it += TOT) {
        int slot = it / 192, d = it - slot * 192;
        int b = slot >> 7, q = slot & 127;
        f32x4 v = {0.f, 0.f, 0.f, 0.f};
        if (q < cntg[b]) {
            int m = offg[b] + q;
            size_t o = (size_t)m * 768 + d * 4;
            v = *(const f32x4*)(P0 + o);
            v += *(const f32x4*)(P0 + 786432 + o);
            v += *(const f32x4*)(p.pb + d * 4);
        }
        *(f32x4*)(p.vis + (size_t)slot * 768 + d * 4) = v;
    }
}

extern "C" void kernel_launch(void* const* d_in, const int* in_sizes, int n_in,
                              void* d_out, int out_size, void* d_ws, size_t ws_size,
                              hipStream_t stream) {
    Pr p;
    p.inputs   = (const float*)d_in[0];
    p.bboxes   = (const int*)d_in[1];
    p.features = (const float*)d_in[2];
    p.t1w = (const float*)d_in[3];  p.t1b = (const float*)d_in[4];
    p.t2w = (const float*)d_in[5];  p.t2b = (const float*)d_in[6];
    p.d1w = (const float*)d_in[7];  p.d1b = (const float*)d_in[8];
    p.d2w = (const float*)d_in[9];  p.d2b = (const float*)d_in[10];
    p.m1w = (const float*)d_in[11]; p.m1b = (const float*)d_in[12];
    p.m2w = (const float*)d_in[13]; p.m2b = (const float*)d_in[14];
    p.pw  = (const float*)d_in[15]; p.pb  = (const float*)d_in[16];

    float* out = (float*)d_out;
    p.vis  = out;
    p.att  = out + 1572864;
    p.retx = out + 1574912;
    p.wsf  = (float*)d_ws;

    int nb = 0;
    hipOccupancyMaxActiveBlocksPerMultiprocessor(&nb, k_fused, 256, 0);
    if (nb < 1) nb = 1;
    int blocks = nb * 256;
    if (blocks > 512) blocks = 512;

    void* args[] = { &p };
    hipLaunchCooperativeKernel((void*)k_fused, dim3(blocks), dim3(256), args, 0, stream);
}

// Round 5
// 699.057 us; speedup vs baseline: 1.1347x; 1.1347x over previous
//
#include <hip/hip_runtime.h>

#define B_ 16
#define T_ 4096
#define D_ 768
#define NBOX 1024
#define MAXBB 128

typedef unsigned short u16;
typedef short bf16x8 __attribute__((ext_vector_type(8)));
typedef float f32x4 __attribute__((ext_vector_type(4)));

// round-to-nearest-even fp32 -> bf16 split: f ~= hi + lo (both bf16)
__device__ __forceinline__ void split_bf(float f, u16& h, u16& l) {
    unsigned u = __builtin_bit_cast(unsigned, f);
    unsigned r = u + 0x7fffu + ((u >> 16) & 1u);
    u16 hb = (u16)(r >> 16);
    float hf = __builtin_bit_cast(float, (unsigned)hb << 16);
    float lf = f - hf;
    unsigned ul = __builtin_bit_cast(unsigned, lf);
    unsigned rl = ul + 0x7fffu + ((ul >> 16) & 1u);
    h = hb; l = (u16)(rl >> 16);
}

struct Pr {
    const float* inputs; const int* bboxes; const float* features;
    const float *t1w, *t1b, *t2w, *t2b, *d1w, *d1b, *d2w, *d2b;
    const float *m1w, *m1b, *m2w, *m2b, *pw, *pb;
    float *vis, *att, *retx;
    float* wsf;
};

// ---- u16-region offsets (units of u16) ----
enum : size_t {
    W6   = 589824,                       // 768*768
    U_T1H = 0,            U_T1L = U_T1H + W6,
    U_T2H = U_T1L + W6,   U_T2L = U_T2H + W6,
    U_D1H = U_T2L + W6,   U_D1L = U_D1H + W6,
    U_D2H = U_D1L + W6,   U_D2L = U_D2H + W6,
    U_M1H = U_D2L + W6,   U_M1L = U_M1H + 196608,
    U_M2H = U_M1L + 196608, U_M2L = U_M2H + W6,
    U_PWH = U_M2L + W6,   U_PWL = U_PWH + 1179648,
    U_FEH = U_PWL + 1179648, U_FEL = U_FEH + 262144,
    U_F1H = U_FEL + 262144,  U_F1L = U_F1H + 786432,
    U_FMH = U_F1L + 786432,  U_FML = U_FMH + 786432,
    U_XPH = U_FML + 786432,  U_XPL = U_XPH + 12288,
    U_XCH = U_XPL + 12288,   U_XCL = U_XCH + 24576,
    U_XTH = U_XCL + 24576,   U_XTL = U_XTH + 12288
};
// ---- fp32-region offsets (units of float) ----
enum : size_t {
    F_PART = 0,
    F_P0   = 786432,                 // 2 slabs of 1024*768
    F_PS   = F_P0 + 2 * 786432,      // 16*1536
    F_BAR  = F_PS + 24576,           // 33 cachelines of barrier state (u32)
    F_CNT  = F_BAR + 33 * 16,        // 32 ints
    F_U16  = F_CNT + 64
};

// ===== fast grid barrier: 32 leaf arrival counters + single release flag ====
// bars[i*16] = leaf i (own 64B line); bars[32*16] = phase flag. Monotonic.
__device__ __forceinline__ void gbar(unsigned* bars, int nb, unsigned phase) {
    __syncthreads();
    if (threadIdx.x == 0) {
        __threadfence();   // release: publish this block's stores (agent scope)
        __hip_atomic_fetch_add(&bars[(blockIdx.x & 31) * 16], 1u,
                               __ATOMIC_RELAXED, __HIP_MEMORY_SCOPE_AGENT);
        if (blockIdx.x == 0) {
            unsigned need = (unsigned)nb * phase;
            for (;;) {
                unsigned s = 0;
                #pragma unroll
                for (int i = 0; i < 32; ++i)
                    s += __hip_atomic_load(&bars[i * 16], __ATOMIC_RELAXED,
                                           __HIP_MEMORY_SCOPE_AGENT);
                if (s >= need) break;
                __builtin_amdgcn_s_sleep(1);
            }
            __threadfence();
            __hip_atomic_store(&bars[32 * 16], phase, __ATOMIC_RELAXED,
                               __HIP_MEMORY_SCOPE_AGENT);
        } else {
            while (__hip_atomic_load(&bars[32 * 16], __ATOMIC_RELAXED,
                                     __HIP_MEMORY_SCOPE_AGENT) < phase)
                __builtin_amdgcn_s_sleep(1);
        }
        __threadfence();   // acquire: see other blocks' stores
    }
    __syncthreads();
}

// ======== 64x64 MFMA wave tile, 3-term in-register, optional gathered A =====
template<int GATHER>
__device__ __forceinline__ void big_wave(const u16* Ah, const u16* Al, int KcA, int akc0,
                                         const u16* Wh, const u16* Wl, int KcW, int wkc0,
                                         int nst, int mt0, int nt0, int lane,
                                         const int* bboxes, float* Pz) {
    f32x4 acc[16];
    #pragma unroll
    for (int i = 0; i < 16; ++i) acc[i] = (f32x4){0.f, 0.f, 0.f, 0.f};
    int img[4];
    if (GATHER) {
        #pragma unroll
        for (int i = 0; i < 4; ++i) img[i] = bboxes[((mt0 + i) * 16 + (lane & 15)) * 5];
    }
    #pragma unroll
    for (int term = 0; term < 3; ++term) {
        const u16* A = (term == 2) ? Al : Ah;
        const u16* W = (term == 1) ? Wl : Wh;
        const u16* Ap[4]; const u16* Wp[4];
        #pragma unroll
        for (int i = 0; i < 4; ++i) {
            if (GATHER) Ap[i] = A + ((size_t)(akc0 + (lane >> 4)) * 16 + img[i]) * 8;
            else        Ap[i] = A + ((size_t)(mt0 + i) * KcA + akc0) * 128 + lane * 8;
            Wp[i] = W + ((size_t)(nt0 + i) * KcW + wkc0) * 128 + lane * 8;
        }
        bf16x8 a[4], b[4];
        #pragma unroll
        for (int i = 0; i < 4; ++i) { a[i] = *(const bf16x8*)Ap[i]; b[i] = *(const bf16x8*)Wp[i]; }
        for (int k = 0; k < nst; ++k) {
            bf16x8 an[4], bn[4];
            if (k + 1 < nst) {
                #pragma unroll
                for (int i = 0; i < 4; ++i) {
                    an[i] = *(const bf16x8*)(Ap[i] + (size_t)(k + 1) * 512);
                    bn[i] = *(const bf16x8*)(Wp[i] + (size_t)(k + 1) * 512);
                }
            }
            #pragma unroll
            for (int i = 0; i < 4; ++i)
                #pragma unroll
                for (int j = 0; j < 4; ++j)
                    acc[i * 4 + j] = __builtin_amdgcn_mfma_f32_16x16x32_bf16(a[i], b[j], acc[i * 4 + j], 0, 0, 0);
            #pragma unroll
            for (int i = 0; i < 4; ++i) { a[i] = an[i]; b[i] = bn[i]; }
        }
    }
    int rb = (lane >> 4) * 4, cb = lane & 15;
    #pragma unroll
    for (int i = 0; i < 4; ++i)
        #pragma unroll
        for (int j = 0; j < 4; ++j) {
            float* pp = Pz + (size_t)((mt0 + i) * 16 + rb) * 768 + (nt0 + j) * 16 + cb;
            f32x4 v = acc[i * 4 + j];
            #pragma unroll
            for (int r = 0; r < 4; ++r) pp[(size_t)r * 768] = v[r];
        }
}

// ======== 16x64 MFMA wave tile (small-M chain), 3-term in-register ==========
__device__ __forceinline__ void small_wave(const u16* Ah, const u16* Al,
                                           const u16* Wh, const u16* Wl,
                                           int KcW, int nst, int ntloc, int nt0g,
                                           int lane, float* Ps) {
    f32x4 acc[4];
    #pragma unroll
    for (int j = 0; j < 4; ++j) acc[j] = (f32x4){0.f, 0.f, 0.f, 0.f};
    #pragma unroll
    for (int term = 0; term < 3; ++term) {
        const u16* A = (term == 2) ? Al : Ah;
        const u16* W = (term == 1) ? Wl : Wh;
        const u16* Ap = A + lane * 8;
        const u16* Wp = W + (size_t)ntloc * KcW * 128 + lane * 8;
        for (int k = 0; k < nst; ++k) {
            bf16x8 a = *(const bf16x8*)(Ap + (size_t)k * 512);
            #pragma unroll
            for (int j = 0; j < 4; ++j) {
                bf16x8 b = *(const bf16x8*)(Wp + (size_t)j * KcW * 128 + (size_t)k * 512);
                acc[j] = __builtin_amdgcn_mfma_f32_16x16x32_bf16(a, b, acc[j], 0, 0, 0);
            }
        }
    }
    int rb = (lane >> 4) * 4, cb = lane & 15;
    #pragma unroll
    for (int j = 0; j < 4; ++j) {
        int col = (nt0g + j) * 16 + cb;
        #pragma unroll
        for (int r = 0; r < 4; ++r) Ps[(size_t)(rb + r) * 1536 + col] = acc[j][r];
    }
}

// ======== pack fp32 GEMM out (1024x768, NS slabs) -> tiled bf16 hi/lo =======
__device__ __forceinline__ void packP(const float* P0, int NS, const float* bias, int relu,
                                      u16* dh, u16* dl, int KcDst, int kcOff, int it) {
    int m = it / 96, kc = it - m * 96;
    const float* s = P0 + (size_t)m * 768 + kc * 8;
    f32x4 v0 = *(const f32x4*)s, v1 = *(const f32x4*)(s + 4);
    if (NS == 2) {
        const float* s2 = s + 786432;
        v0 += *(const f32x4*)s2; v1 += *(const f32x4*)(s2 + 4);
    }
    v0 += *(const f32x4*)(bias + kc * 8);
    v1 += *(const f32x4*)(bias + kc * 8 + 4);
    bf16x8 hv, lv;
    #pragma unroll
    for (int j = 0; j < 4; ++j) {
        float a = relu ? fmaxf(v0[j], 0.f) : v0[j];
        float b = relu ? fmaxf(v1[j], 0.f) : v1[j];
        u16 h, l;
        split_bf(a, h, l); hv[j] = (short)h; lv[j] = (short)l;
        split_bf(b, h, l); hv[4 + j] = (short)h; lv[4 + j] = (short)l;
    }
    size_t off = ((size_t)(m >> 4) * KcDst + kcOff + kc) * 128 + (m & 15) * 8;
    *(bf16x8*)(dh + off) = hv;
    *(bf16x8*)(dl + off) = lv;
}

__global__ __launch_bounds__(256, 2) void k_fused(Pr p) {
    const int NB = gridDim.x;
    const int TOT = NB * 256;
    const int tg = blockIdx.x * 256 + threadIdx.x;
    const int lane = threadIdx.x & 63;
    const int wvl = threadIdx.x >> 6;
    const int wv = wvl * NB + blockIdx.x;   // spread wave-item id

    float* part = p.wsf + F_PART;
    float* P0   = p.wsf + F_P0;
    float* Ps   = p.wsf + F_PS;
    unsigned* bars = (unsigned*)(p.wsf + F_BAR);
    int*   cntg = (int*)(p.wsf + F_CNT);
    int*   offg = cntg + 16;
    u16*   U    = (u16*)(p.wsf + F_U16);

    __shared__ int scnt[B_];
    __shared__ int soff[B_];

    // =========== Ph0: mean-partials + all packs + meta (independent) =========
    {   // mean partial: 16*64 chunks x 192 f4-cols
        const float4* in4 = (const float4*)p.inputs;
        for (int it = tg; it < 196608; it += TOT) {
            int chunk = it / 192, t = it - chunk * 192;
            int b = chunk >> 6, cs = chunk & 63;
            const float4* base = in4 + (size_t)b * (T_ * D_ / 4) + (size_t)cs * 12288 + t;
            float4 s = {0.f, 0.f, 0.f, 0.f};
            #pragma unroll 4
            for (int r = 0; r < 64; ++r) {
                float4 v = base[(size_t)r * 192];
                s.x += v.x; s.y += v.y; s.z += v.z; s.w += v.w;
            }
            ((float4*)part)[it] = s;
        }
    }
    {   // weight packs: 7 matrices
        const float* srcs[7] = {p.t1w, p.t2w, p.d1w, p.d2w, p.m1w, p.m2w, p.pw};
        u16* his[7] = {U + U_T1H, U + U_T2H, U + U_D1H, U + U_D2H, U + U_M1H, U + U_M2H, U + U_PWH};
        u16* los[7] = {U + U_T1L, U + U_T2L, U + U_D1L, U + U_D2L, U + U_M1L, U + U_M2L, U + U_PWL};
        const int Kcs[7] = {96, 96, 96, 96, 32, 96, 192};
        #pragma unroll 1
        for (int mi = 0; mi < 7; ++mi) {
            int Kc = Kcs[mi];
            int cnt = 768 * Kc;
            const float* src = srcs[mi];
            u16 *dh = his[mi], *dl = los[mi];
            for (int it = tg; it < cnt; it += TOT) {
                int n = it / Kc, kc = it - n * Kc;
                const float* s = src + (size_t)n * (Kc * 8) + kc * 8;
                f32x4 v0 = *(const f32x4*)s, v1 = *(const f32x4*)(s + 4);
                bf16x8 hv, lv;
                #pragma unroll
                for (int j = 0; j < 4; ++j) {
                    u16 h, l;
                    split_bf(v0[j], h, l); hv[j] = (short)h; lv[j] = (short)l;
                    split_bf(v1[j], h, l); hv[4 + j] = (short)h; lv[4 + j] = (short)l;
                }
                size_t off = ((size_t)(n >> 4) * Kc + kc) * 128 + (n & 15) * 8;
                *(bf16x8*)(dh + off) = hv;
                *(bf16x8*)(dl + off) = lv;
            }
        }
    }
    {   // feat pack (misaligned stride-257 source)
        for (int it = tg; it < NBOX * 32; it += TOT) {
            int i = it >> 5, kc = it & 31;
            const float* s = p.features + (size_t)i * 257 + 1 + kc * 8;
            bf16x8 hv, lv;
            #pragma unroll
            for (int j = 0; j < 8; ++j) {
                u16 h, l;
                split_bf(s[j], h, l); hv[j] = (short)h; lv[j] = (short)l;
            }
            size_t off = ((size_t)(i >> 4) * 32 + kc) * 128 + (i & 15) * 8;
            *(bf16x8*)(U + U_FEH + off) = hv;
            *(bf16x8*)(U + U_FEL + off) = lv;
        }
    }
    if (blockIdx.x == 0) {   // meta: counts / offsets / att_mask
        int tid = threadIdx.x;
        if (tid < B_) scnt[tid] = 0;
        __syncthreads();
        for (int i = tid; i < NBOX; i += 256) atomicAdd(&scnt[p.bboxes[i * 5]], 1);
        __syncthreads();
        if (tid == 0) {
            int acc = 0;
            for (int b = 0; b < B_; ++b) { soff[b] = acc; acc += scnt[b]; }
        }
        __syncthreads();
        if (tid < B_) { cntg[tid] = scnt[tid]; offg[tid] = soff[tid]; }
        for (int j = tid; j < B_ * MAXBB; j += 256) {
            int b = j >> 7, q = j & 127;
            p.att[j] = (q < scnt[b]) ? 1.0f : 0.0f;
        }
    }
    gbar(bars, NB, 1);

    // =========== Ph1: mean final + pack x ====================================
    for (int it = tg; it < 1536; it += TOT) {
        int b = it / 96, kc = it - b * 96;
        f32x4 s0 = {0,0,0,0}, s1 = {0,0,0,0};
        for (int c = 0; c < 64; ++c) {
            const float* q = part + (size_t)(b * 64 + c) * 768 + kc * 8;
            s0 += *(const f32x4*)q; s1 += *(const f32x4*)(q + 4);
        }
        const float inv = 1.0f / T_;
        bf16x8 hv, lv;
        #pragma unroll
        for (int j = 0; j < 4; ++j) {
            u16 h, l;
            split_bf(s0[j] * inv, h, l); hv[j] = (short)h; lv[j] = (short)l;
            split_bf(s1[j] * inv, h, l); hv[4 + j] = (short)h; lv[4 + j] = (short)l;
        }
        size_t off = ((size_t)kc * 16 + b) * 8;
        *(bf16x8*)(U + U_XPH + off) = hv;
        *(bf16x8*)(U + U_XPL + off) = lv;
    }
    gbar(bars, NB, 2);

    // =========== Ph2: small layer1 + fm1 GEMM ================================
    if (wv < 24) {
        int nt0g = wv * 4;
        int path = nt0g >= 48;
        int ntloc = nt0g - 48 * path;
        small_wave(U + U_XPH, U + U_XPL,
                   U + (path ? U_T1H : U_D1H), U + (path ? U_T1L : U_D1L),
                   96, 24, ntloc, nt0g, lane, Ps);
    } else if (wv < 216) {
        int t = wv - 24;
        big_wave<0>(U + U_FEH, U + U_FEL, 32, 0,
                    U + U_M1H, U + U_M1L, 32, 0,
                    8, (t / 12) * 4, (t % 12) * 4, lane, nullptr, P0);
    }
    gbar(bars, NB, 3);

    // =========== Ph3: sepi1 (xc pack) + fm1 pack =============================
    for (int it = tg; it < 3072 + 98304; it += TOT) {
        if (it < 3072) {
            int r = it / 192, cc = it - r * 192;
            const float* q = Ps + (size_t)r * 1536 + cc * 8;
            f32x4 s0 = *(const f32x4*)q, s1 = *(const f32x4*)(q + 4);
            int path = cc >= 96;
            int ccp = cc - path * 96;
            const float* bias = (path ? p.t1b : p.d1b) + ccp * 8;
            s0 += *(const f32x4*)bias; s1 += *(const f32x4*)(bias + 4);
            bf16x8 hv, lv;
            #pragma unroll
            for (int j = 0; j < 4; ++j) {
                u16 h, l;
                split_bf(fmaxf(s0[j], 0.f), h, l); hv[j] = (short)h; lv[j] = (short)l;
                split_bf(fmaxf(s1[j], 0.f), h, l); hv[4 + j] = (short)h; lv[4 + j] = (short)l;
            }
            size_t off = (size_t)path * 12288 + ((size_t)ccp * 16 + r) * 8;
            *(bf16x8*)(U + U_XCH + off) = hv;
            *(bf16x8*)(U + U_XCL + off) = lv;
        } else {
            packP(P0, 1, p.m1b, 1, U + U_F1H, U + U_F1L, 96, 0, it - 3072);
        }
    }
    gbar(bars, NB, 4);

    // =========== Ph4: small layer2 + fm GEMM (KS=2) ==========================
    if (wv < 24) {
        int nt0g = wv * 4;
        int path = nt0g >= 48;
        int ntloc = nt0g - 48 * path;
        small_wave(U + U_XCH + path * 12288, U + U_XCL + path * 12288,
                   U + (path ? U_T2H : U_D2H), U + (path ? U_T2L : U_D2L),
                   96, 24, ntloc, nt0g, lane, Ps);
    } else if (wv < 408) {
        int u = wv - 24;
        int z = u / 192, tt = u - z * 192;
        big_wave<0>(U + U_F1H, U + U_F1L, 96, z * 48,
                    U + U_M2H, U + U_M2L, 96, z * 48,
                    12, (tt / 12) * 4, (tt % 12) * 4, lane, nullptr, P0 + (size_t)z * 786432);
    }
    gbar(bars, NB, 5);

    // =========== Ph5: sepi2 (retx + xt pack) + fm pack (NS=2) ================
    for (int it = tg; it < 3072 + 98304; it += TOT) {
        if (it < 3072) {
            int r = it / 192, cc = it - r * 192;
            const float* q = Ps + (size_t)r * 1536 + cc * 8;
            f32x4 s0 = *(const f32x4*)q, s1 = *(const f32x4*)(q + 4);
            int path = cc >= 96;
            int ccp = cc - path * 96;
            const float* bias = (path ? p.t2b : p.d2b) + ccp * 8;
            s0 += *(const f32x4*)bias; s1 += *(const f32x4*)(bias + 4);
            if (!path) {
                float* o = p.retx + (size_t)r * 768 + ccp * 8;
                *(f32x4*)o = s0; *(f32x4*)(o + 4) = s1;
            } else {
                bf16x8 hv, lv;
                #pragma unroll
                for (int j = 0; j < 4; ++j) {
                    u16 h, l;
                    split_bf(s0[j], h, l); hv[j] = (short)h; lv[j] = (short)l;
                    split_bf(s1[j], h, l); hv[4 + j] = (short)h; lv[4 + j] = (short)l;
                }
                size_t off = ((size_t)ccp * 16 + r) * 8;
                *(bf16x8*)(U + U_XTH + off) = hv;
                *(bf16x8*)(U + U_XTL + off) = lv;
            }
        } else {
            packP(P0, 2, p.m2b, 0, U + U_FMH, U + U_FML, 96, 0, it - 3072);
        }
    }
    gbar(bars, NB, 6);

    // =========== Ph6: h GEMM (KS=2: z0 = gathered xt half, z1 = fm half) =====
    if (wv < 384) {
        int z = wv / 192, tt = wv - z * 192;
        int mt0 = (tt / 12) * 4, nt0 = (tt % 12) * 4;
        if (z == 0)
            big_wave<1>(U + U_XTH, U + U_XTL, 96, 0,
                        U + U_PWH, U + U_PWL, 192, 0,
                        24, mt0, nt0, lane, p.bboxes, P0);
        else
            big_wave<0>(U + U_FMH, U + U_FML, 96, 0,
                        U + U_PWH, U + U_PWL, 192, 96,
                        24, mt0, nt0, lane, nullptr, P0 + 786432);
    }
    gbar(bars, NB, 7);

    // =========== Ph7: vis epilogue (sum 2 slabs + pb, scatter-by-slot) =======
    for (int it = tg; it < B_ * MAXBB * 192; it += TOT) {
        int slot = it / 192, d = it - slot * 192;
        int b = slot >> 7, q = slot & 127;
        f32x4 v = {0.f, 0.f, 0.f, 0.f};
        if (q < cntg[b]) {
            int m = offg[b] + q;
            size_t o = (size_t)m * 768 + d * 4;
            v = *(const f32x4*)(P0 + o);
            v += *(const f32x4*)(P0 + 786432 + o);
            v += *(const f32x4*)(p.pb + d * 4);
        }
        *(f32x4*)(p.vis + (size_t)slot * 768 + d * 4) = v;
    }
}

extern "C" void kernel_launch(void* const* d_in, const int* in_sizes, int n_in,
                              void* d_out, int out_size, void* d_ws, size_t ws_size,
                              hipStream_t stream) {
    Pr p;
    p.inputs   = (const float*)d_in[0];
    p.bboxes   = (const int*)d_in[1];
    p.features = (const float*)d_in[2];
    p.t1w = (const float*)d_in[3];  p.t1b = (const float*)d_in[4];
    p.t2w = (const float*)d_in[5];  p.t2b = (const float*)d_in[6];
    p.d1w = (const float*)d_in[7];  p.d1b = (const float*)d_in[8];
    p.d2w = (const float*)d_in[9];  p.d2b = (const float*)d_in[10];
    p.m1w = (const float*)d_in[11]; p.m1b = (const float*)d_in[12];
    p.m2w = (const float*)d_in[13]; p.m2b = (const float*)d_in[14];
    p.pw  = (const float*)d_in[15]; p.pb  = (const float*)d_in[16];

    float* out = (float*)d_out;
    p.vis  = out;
    p.att  = out + 1572864;
    p.retx = out + 1574912;
    p.wsf  = (float*)d_ws;

    // zero the barrier state (33 x 64B cachelines) — graph-capture-safe
    hipMemsetAsync((void*)(p.wsf + F_BAR), 0, 33 * 64, stream);

    int nb = 0;
    hipOccupancyMaxActiveBlocksPerMultiprocessor(&nb, k_fused, 256, 0);
    if (nb < 1) nb = 1;
    int blocks = nb * 256;
    if (blocks > 1024) blocks = 1024;
    if (blocks < 128)  blocks = 128;

    void* args[] = { &p };
    hipLaunchCooperativeKernel((void*)k_fused, dim3(blocks), dim3(256), args, 0, stream);
}